// Round 9
// baseline (2023.312 us; speedup 1.0000x reference)
//
#include <hip/hip_runtime.h>
#include <stdint.h>

#define L_DIM 2048
#define B_DIM 32
#define D_DIM 1024
#define N_DIM 3072   // 3*D
#define K_DIM 1024
#define BD    32768  // B*D

typedef __bf16 bf16x8 __attribute__((ext_vector_type(8)));
typedef unsigned short ushort8 __attribute__((ext_vector_type(8)));
typedef float f32x4 __attribute__((ext_vector_type(4)));

typedef const __attribute__((address_space(1))) unsigned int* gq_t;
typedef __attribute__((address_space(3))) unsigned int* lq_t;

static __device__ __forceinline__ unsigned short f2bf(float f) {
  unsigned u = __float_as_uint(f);
  u += 0x7FFFu + ((u >> 16) & 1u);   // RNE
  return (unsigned short)(u >> 16);
}

static __device__ __forceinline__ float bf2f(unsigned short s) {
  return __uint_as_float(((unsigned)s) << 16);
}

// ---------- convert ALL of x (f32) -> bf16, 8 elems/thread, one pass ----------
__global__ void k_convx(const float* __restrict__ x, unsigned short* __restrict__ xb, int n8) {
  int i = blockIdx.x * blockDim.x + threadIdx.x;
  if (i >= n8) return;
  const float4* p = reinterpret_cast<const float4*>(x) + (size_t)i * 2;
  float4 a = p[0], b = p[1];
  ushort8 o;
  o[0] = f2bf(a.x); o[1] = f2bf(a.y); o[2] = f2bf(a.z); o[3] = f2bf(a.w);
  o[4] = f2bf(b.x); o[5] = f2bf(b.y); o[6] = f2bf(b.z); o[7] = f2bf(b.w);
  reinterpret_cast<ushort8*>(xb)[i] = o;
}

// ---------- W (K,N=3072 interleaved 3d+k) f32 -> WT (N'=k*D+d, K) bf16 ----------
__global__ __launch_bounds__(256) void k_wt(const float* __restrict__ w, unsigned short* __restrict__ wt) {
  __shared__ unsigned short tile[64][65];
  const int bid = blockIdx.x;
  const int kb = bid & 15;          // K/64 tile
  const int db = (bid >> 4) & 15;   // D/64 tile
  const int kp = bid >> 8;          // plane 0..2
  const int t = threadIdx.x;
  const int c = t & 63;
  const int q = t >> 6;             // 0..3
#pragma unroll
  for (int i = 0; i < 16; ++i) {
    int r = q * 16 + i;             // k within tile
    float v = w[(size_t)(kb * 64 + r) * N_DIM + 3 * (db * 64 + c) + kp];
    tile[r][c] = f2bf(v);
  }
  __syncthreads();
  const int k = t & 63;
#pragma unroll
  for (int i = 0; i < 16; ++i) {
    int n = q * 16 + i;             // d within tile
    wt[(size_t)(kp * D_DIM + db * 64 + n) * K_DIM + kb * 64 + k] = tile[k][n];
  }
}

// ---------- per-column bias, plane layout: col j = k*D+d ----------
__global__ void k_biascol(const float* __restrict__ bias, float* __restrict__ bc) {
  int j = blockIdx.x * blockDim.x + threadIdx.x;
  if (j >= N_DIM) return;
  int k = j >> 10;
  int d = j & 1023;
  float v = 0.f;
  if (k == 1) v = bias[d];
  else if (k == 2) v = bias[D_DIM + d];
  bc[j] = v;
}

// ---------- 256x256 8-phase bf16 MFMA GEMM (T1+T2+T3+T4+T5), bn-fast ----------
__global__ __launch_bounds__(512, 2) void k_gemm(
    const unsigned short* __restrict__ A,
    const unsigned short* __restrict__ BT,
    const float* __restrict__ bc,
    unsigned short* __restrict__ C,
    int Mtiles)
{
  __shared__ unsigned short smem[65536];

  // --- block swizzle (bijective, 8 XCDs); bn fast so same-XCD neighbors share A panel
  const int nwg = gridDim.x;
  const int q8 = nwg >> 3, r8 = nwg & 7;
  const int xcd = blockIdx.x & 7, li = blockIdx.x >> 3;
  const int wg = (xcd < r8 ? xcd * (q8 + 1) : r8 * (q8 + 1) + (xcd - r8) * q8) + li;
  const int NT = N_DIM / 256;   // 12
  const int bn = wg % NT;
  const int bm = wg / NT;

  const int t  = threadIdx.x;
  const int w  = t >> 6;
  const int l  = t & 63;
  const int wr = w >> 2, wc = w & 3;
  const int wrb = wr * 128, wcb = wc * 64;
  const int l15 = l & 15, lg = l >> 4, lx = l & 7;
  const int kgp0 = (lg ^ lx) * 8;          // elem offset of ksub=0 octet
  const int kgp1 = ((4 + lg) ^ lx) * 8;    // ksub=1
  const int sr0 = w * 8 + (l >> 3);        // staging row within half
  const int kgs = (lx ^ (l >> 3)) * 8;     // swizzled source k-octet

  const unsigned short* Abase = A  + (size_t)(bm * 256) * K_DIM;
  const unsigned short* Bbase = BT + (size_t)(bn * 256) * K_DIM;

  f32x4 acc[8][4];
#pragma unroll
  for (int i = 0; i < 8; ++i)
#pragma unroll
    for (int j = 0; j < 4; ++j) acc[i][j] = f32x4{0.f, 0.f, 0.f, 0.f};

#define STAGE(G, growbase, T, ldsBase)                                                  \
  { const unsigned short* s0_ = (G) + (((size_t)((growbase) + sr0)) << 10) + (T) * 64 + kgs; \
    __builtin_amdgcn_global_load_lds((gq_t)s0_, (lq_t)&smem[(ldsBase) + w * 512], 16, 0, 0); \
    const unsigned short* s1_ = s0_ + (64 << 10);                                       \
    __builtin_amdgcn_global_load_lds((gq_t)s1_, (lq_t)&smem[(ldsBase) + 4096 + w * 512], 16, 0, 0); }

#define SB0(T, b) STAGE(Bbase, 0,   (T), (b) * 32768 + 16384)
#define SB1(T, b) STAGE(Bbase, 128, (T), (b) * 32768 + 16384 + 8192)
#define SA0(T, b) STAGE(Abase, 0,   (T), (b) * 32768)
#define SA1(T, b) STAGE(Abase, 128, (T), (b) * 32768 + 8192)

#define LDF(idx) __builtin_bit_cast(bf16x8, *reinterpret_cast<const ushort8*>(&smem[(idx)]))

  // ---- prologue: tile0 fully + SB0(1); wait tile0, SB0(1) stays in flight
  SB0(0, 0); SB1(0, 0); SA0(0, 0); SA1(0, 0); SB0(1, 1);
  asm volatile("s_waitcnt vmcnt(2)" ::: "memory");
  __builtin_amdgcn_s_barrier();

#pragma unroll 2
  for (int t0 = 0; t0 < 16; ++t0) {
    const int cur = t0 & 1, nxt = cur ^ 1;
    const int cA = cur * 32768, cB = cA + 16384;
    bf16x8 bfr[4][2];
#pragma unroll
    for (int q = 0; q < 4; ++q) {
      bf16x8 af[2][2];
      if (q == 0) {
#pragma unroll
        for (int nf = 0; nf < 4; ++nf) {
          const int nr = (wcb + nf * 16 + l15) * 64;
          bfr[nf][0] = LDF(cB + nr + kgp0);
          bfr[nf][1] = LDF(cB + nr + kgp1);
        }
      }
#pragma unroll
      for (int mf = 0; mf < 2; ++mf) {
        const int ar = (wrb + (q * 2 + mf) * 16 + l15) * 64;
        af[mf][0] = LDF(cA + ar + kgp0);
        af[mf][1] = LDF(cA + ar + kgp1);
      }
      if (q == 0 && t0 < 15) SB1(t0 + 1, nxt);
      if (q == 1 && t0 < 15) SA0(t0 + 1, nxt);
      if (q == 2 && t0 < 15) SA1(t0 + 1, nxt);
      if (q == 3 && t0 < 14) SB0(t0 + 2, cur);

      __builtin_amdgcn_s_barrier();
      __builtin_amdgcn_s_setprio(1);
#pragma unroll
      for (int mf = 0; mf < 2; ++mf)
#pragma unroll
        for (int nf = 0; nf < 4; ++nf) {
          acc[q * 2 + mf][nf] = __builtin_amdgcn_mfma_f32_16x16x32_bf16(af[mf][0], bfr[nf][0], acc[q * 2 + mf][nf], 0, 0, 0);
          acc[q * 2 + mf][nf] = __builtin_amdgcn_mfma_f32_16x16x32_bf16(af[mf][1], bfr[nf][1], acc[q * 2 + mf][nf], 0, 0, 0);
        }
      __builtin_amdgcn_s_setprio(0);
      if (q == 3) {
        if (t0 < 14)       asm volatile("s_waitcnt vmcnt(2)" ::: "memory");
        else if (t0 == 14) asm volatile("s_waitcnt vmcnt(0)" ::: "memory");
      }
      __builtin_amdgcn_s_barrier();
      __builtin_amdgcn_sched_barrier(0);
    }
  }

  // ---- epilogue: bias add, f32->bf16, store
  const int r4 = lg * 4;
  float badd[4];
#pragma unroll
  for (int nf = 0; nf < 4; ++nf) badd[nf] = bc[bn * 256 + wcb + nf * 16 + l15];
#pragma unroll
  for (int fm = 0; fm < 8; ++fm) {
    const int row = bm * 256 + wrb + fm * 16 + r4;
#pragma unroll
    for (int nf = 0; nf < 4; ++nf) {
      const int col = bn * 256 + wcb + nf * 16 + l15;
      unsigned short* out = C + (size_t)row * N_DIM + col;
#pragma unroll
      for (int i = 0; i < 4; ++i)
        out[(size_t)i * N_DIM] = f2bf(acc[fm][nf][i] + badd[nf]);
    }
  }
#undef STAGE
#undef SB0
#undef SB1
#undef SA0
#undef SA1
#undef LDF
}

// ---------- SRU recurrence over a chunk of Lc steps ----------
// Grid-limited to 2 waves/CU: tell the allocator occupancy doesn't matter
// so it keeps ~128 loads in flight across the serial c-chain.
__global__ __launch_bounds__(64, 1) void k_rec(
    const unsigned short* __restrict__ xb,  // chunk (Lc, BD) bf16
    const unsigned short* __restrict__ u3,  // chunk (Lc*32, 3072) bf16 planes
    const float* __restrict__ wcv,
    const float* __restrict__ sxp,
    float* __restrict__ c_state,            // (BD)
    float* __restrict__ h,                  // chunk base (Lc, BD) f32
    int Lc)
{
  int tid = blockIdx.x * 64 + threadIdx.x;
  const int d = tid & (D_DIM - 1);
  const int b = tid >> 10;
  const float fw = wcv[d];
  const float rw = wcv[D_DIM + d];
  const float sx = sxp[0];
  float c = c_state[tid];

  const unsigned short* up = u3 + (size_t)b * N_DIM + d;
  const unsigned short* xp = xb + tid;
  float*                hp = h + tid;

#pragma unroll 32
  for (int l = 0; l < Lc; ++l) {
    float u0 = bf2f(up[0]);
    float u1 = bf2f(up[1024]);
    float u2 = bf2f(up[2048]);
    float xv = bf2f(xp[0]) * sx;
    float f = 1.f / (1.f + __expf(-(u1 + c * fw)));
    float r = 1.f / (1.f + __expf(-(u2 + c * rw)));
    c = u0 + (c - u0) * f;
    hp[0] = xv + (c - xv) * r;
    up += (size_t)32 * N_DIM;
    xp += BD;
    hp += BD;
  }
  c_state[tid] = c;
}

__global__ void k_copyc(const float* __restrict__ c_state, float* __restrict__ out) {
  int i = blockIdx.x * blockDim.x + threadIdx.x;
  if (i < BD) out[i] = c_state[i];
}

extern "C" void kernel_launch(void* const* d_in, const int* in_sizes, int n_in,
                              void* d_out, int out_size, void* d_ws, size_t ws_size,
                              hipStream_t stream) {
  const float* x    = (const float*)d_in[0];
  const float* w    = (const float*)d_in[1];
  const float* wcv  = (const float*)d_in[2];
  const float* bias = (const float*)d_in[3];
  const float* sx   = (const float*)d_in[4];
  float* hout = (float*)d_out;
  float* cout = hout + (size_t)L_DIM * BD;

  const size_t wt_bytes  = (size_t)N_DIM * K_DIM * 2;
  const size_t bc_off    = wt_bytes;
  const size_t c_off     = bc_off + (size_t)N_DIM * 4;
  const size_t xbf_off   = c_off + (size_t)BD * 4;
  const size_t xbf_bytes = (size_t)L_DIM * BD * 2;   // full-x bf16: 134 MB
  const size_t u3_off    = xbf_off + xbf_bytes;
  int Lc = 8;
  for (int cand : {512, 256, 128, 64, 32, 16, 8}) {
    size_t need = u3_off + (size_t)cand * 196608 + 1024;   // u3 chunk bf16
    if (need <= ws_size) { Lc = cand; break; }
  }
  char* wsb = (char*)d_ws;
  unsigned short* wt_p  = (unsigned short*)wsb;
  float*          bc_p  = (float*)(wsb + bc_off);
  float*          c_p   = (float*)(wsb + c_off);
  unsigned short* xbf_p = (unsigned short*)(wsb + xbf_off);
  unsigned short* u3_p  = (unsigned short*)(wsb + u3_off);

  hipMemsetAsync(c_p, 0, (size_t)BD * 4, stream);
  k_wt<<<(K_DIM / 64) * (D_DIM / 64) * 3, 256, 0, stream>>>(w, wt_p);
  k_biascol<<<(N_DIM + 255) / 256, 256, 0, stream>>>(bias, bc_p);
  k_convx<<<(L_DIM * BD / 8) / 256, 256, 0, stream>>>(x, xbf_p, L_DIM * BD / 8);

  const int nchunks = L_DIM / Lc;
  const int Mtiles  = (Lc * B_DIM) / 256;
  for (int ci = 0; ci < nchunks; ++ci) {
    const size_t base = (size_t)ci * Lc * BD;
    k_gemm<<<Mtiles * (N_DIM / 256), 512, 0, stream>>>(xbf_p + base, wt_p, bc_p, u3_p, Mtiles);
    k_rec<<<BD / 64, 64, 0, stream>>>(xbf_p + base, u3_p, wcv, sx, c_p, hout + base, Lc);
  }
  k_copyc<<<BD / 256, 256, 0, stream>>>(c_p, cout);
}

// Round 10
// 1428.672 us; speedup vs baseline: 1.4162x; 1.4162x over previous
//
#include <hip/hip_runtime.h>
#include <stdint.h>

#define L_DIM 2048
#define B_DIM 32
#define D_DIM 1024
#define N_DIM 3072   // 3*D
#define K_DIM 1024
#define BD    32768  // B*D

typedef __bf16 bf16x8 __attribute__((ext_vector_type(8)));
typedef unsigned short ushort8 __attribute__((ext_vector_type(8)));
typedef float f32x4 __attribute__((ext_vector_type(4)));

typedef const __attribute__((address_space(1))) unsigned int* gq_t;
typedef __attribute__((address_space(3))) unsigned int* lq_t;

static __device__ __forceinline__ unsigned short f2bf(float f) {
  unsigned u = __float_as_uint(f);
  u += 0x7FFFu + ((u >> 16) & 1u);   // RNE
  return (unsigned short)(u >> 16);
}

static __device__ __forceinline__ float bf2f(unsigned short s) {
  return __uint_as_float(((unsigned)s) << 16);
}

// ---------- convert ALL of x (f32) -> bf16, 8 elems/thread, one pass ----------
__global__ void k_convx(const float* __restrict__ x, unsigned short* __restrict__ xb, int n8) {
  int i = blockIdx.x * blockDim.x + threadIdx.x;
  if (i >= n8) return;
  const float4* p = reinterpret_cast<const float4*>(x) + (size_t)i * 2;
  float4 a = p[0], b = p[1];
  ushort8 o;
  o[0] = f2bf(a.x); o[1] = f2bf(a.y); o[2] = f2bf(a.z); o[3] = f2bf(a.w);
  o[4] = f2bf(b.x); o[5] = f2bf(b.y); o[6] = f2bf(b.z); o[7] = f2bf(b.w);
  reinterpret_cast<ushort8*>(xb)[i] = o;
}

// ---------- W (K, N=3072 cols j=3d+k) f32 -> WT (N, K) bf16, straight transpose ----------
__global__ __launch_bounds__(256) void k_wt(const float* __restrict__ w, unsigned short* __restrict__ wt) {
  __shared__ unsigned short tile[64][65];
  const int kb = blockIdx.x & 15;        // K/64 tile
  const int nb = blockIdx.x >> 4;        // N/64 tile 0..47
  const int t = threadIdx.x;
  const int c = t & 63;
  const int q = t >> 6;                  // 0..3
#pragma unroll
  for (int i = 0; i < 16; ++i) {
    int r = q * 16 + i;                  // k within tile
    tile[r][c] = f2bf(w[(size_t)(kb * 64 + r) * N_DIM + nb * 64 + c]);
  }
  __syncthreads();
  const int k = t & 63;
#pragma unroll
  for (int i = 0; i < 16; ++i) {
    int n = q * 16 + i;                  // n within tile
    wt[(size_t)(nb * 64 + n) * K_DIM + kb * 64 + k] = tile[k][n];
  }
}

// ---------- per-column bias, interleaved layout: col j = 3d+k ----------
__global__ void k_biascol(const float* __restrict__ bias, float* __restrict__ bc) {
  int j = blockIdx.x * blockDim.x + threadIdx.x;
  if (j >= N_DIM) return;
  int d = j / 3;
  int k = j - 3 * d;
  float v = 0.f;
  if (k == 1) v = bias[d];
  else if (k == 2) v = bias[D_DIM + d];
  bc[j] = v;
}

// ---------- 256x256 8-phase bf16 MFMA GEMM (T1+T2+T3+T4+T5), bn-fast ----------
__global__ __launch_bounds__(512, 2) void k_gemm(
    const unsigned short* __restrict__ A,
    const unsigned short* __restrict__ BT,
    const float* __restrict__ bc,
    unsigned short* __restrict__ C,
    int Mtiles)
{
  __shared__ unsigned short smem[65536];

  // --- block swizzle (bijective, 8 XCDs); bn fast so same-XCD neighbors share A panel
  const int nwg = gridDim.x;
  const int q8 = nwg >> 3, r8 = nwg & 7;
  const int xcd = blockIdx.x & 7, li = blockIdx.x >> 3;
  const int wg = (xcd < r8 ? xcd * (q8 + 1) : r8 * (q8 + 1) + (xcd - r8) * q8) + li;
  const int NT = N_DIM / 256;   // 12
  const int bn = wg % NT;
  const int bm = wg / NT;

  const int t  = threadIdx.x;
  const int w  = t >> 6;
  const int l  = t & 63;
  const int wr = w >> 2, wc = w & 3;
  const int wrb = wr * 128, wcb = wc * 64;
  const int l15 = l & 15, lg = l >> 4, lx = l & 7;
  const int kgp0 = (lg ^ lx) * 8;          // elem offset of ksub=0 octet
  const int kgp1 = ((4 + lg) ^ lx) * 8;    // ksub=1
  const int sr0 = w * 8 + (l >> 3);        // staging row within half
  const int kgs = (lx ^ (l >> 3)) * 8;     // swizzled source k-octet

  const unsigned short* Abase = A  + (size_t)(bm * 256) * K_DIM;
  const unsigned short* Bbase = BT + (size_t)(bn * 256) * K_DIM;

  f32x4 acc[8][4];
#pragma unroll
  for (int i = 0; i < 8; ++i)
#pragma unroll
    for (int j = 0; j < 4; ++j) acc[i][j] = f32x4{0.f, 0.f, 0.f, 0.f};

#define STAGE(G, growbase, T, ldsBase)                                                  \
  { const unsigned short* s0_ = (G) + (((size_t)((growbase) + sr0)) << 10) + (T) * 64 + kgs; \
    __builtin_amdgcn_global_load_lds((gq_t)s0_, (lq_t)&smem[(ldsBase) + w * 512], 16, 0, 0); \
    const unsigned short* s1_ = s0_ + (64 << 10);                                       \
    __builtin_amdgcn_global_load_lds((gq_t)s1_, (lq_t)&smem[(ldsBase) + 4096 + w * 512], 16, 0, 0); }

#define SB0(T, b) STAGE(Bbase, 0,   (T), (b) * 32768 + 16384)
#define SB1(T, b) STAGE(Bbase, 128, (T), (b) * 32768 + 16384 + 8192)
#define SA0(T, b) STAGE(Abase, 0,   (T), (b) * 32768)
#define SA1(T, b) STAGE(Abase, 128, (T), (b) * 32768 + 8192)

#define LDF(idx) __builtin_bit_cast(bf16x8, *reinterpret_cast<const ushort8*>(&smem[(idx)]))

  // ---- prologue: tile0 fully + SB0(1); wait tile0, SB0(1) stays in flight
  SB0(0, 0); SB1(0, 0); SA0(0, 0); SA1(0, 0); SB0(1, 1);
  asm volatile("s_waitcnt vmcnt(2)" ::: "memory");
  __builtin_amdgcn_s_barrier();

#pragma unroll 2
  for (int t0 = 0; t0 < 16; ++t0) {
    const int cur = t0 & 1, nxt = cur ^ 1;
    const int cA = cur * 32768, cB = cA + 16384;
    bf16x8 bfr[4][2];
#pragma unroll
    for (int q = 0; q < 4; ++q) {
      bf16x8 af[2][2];
      if (q == 0) {
#pragma unroll
        for (int nf = 0; nf < 4; ++nf) {
          const int nr = (wcb + nf * 16 + l15) * 64;
          bfr[nf][0] = LDF(cB + nr + kgp0);
          bfr[nf][1] = LDF(cB + nr + kgp1);
        }
      }
#pragma unroll
      for (int mf = 0; mf < 2; ++mf) {
        const int ar = (wrb + (q * 2 + mf) * 16 + l15) * 64;
        af[mf][0] = LDF(cA + ar + kgp0);
        af[mf][1] = LDF(cA + ar + kgp1);
      }
      if (q == 0 && t0 < 15) SB1(t0 + 1, nxt);
      if (q == 1 && t0 < 15) SA0(t0 + 1, nxt);
      if (q == 2 && t0 < 15) SA1(t0 + 1, nxt);
      if (q == 3 && t0 < 14) SB0(t0 + 2, cur);

      __builtin_amdgcn_s_barrier();
      __builtin_amdgcn_s_setprio(1);
#pragma unroll
      for (int mf = 0; mf < 2; ++mf)
#pragma unroll
        for (int nf = 0; nf < 4; ++nf) {
          acc[q * 2 + mf][nf] = __builtin_amdgcn_mfma_f32_16x16x32_bf16(af[mf][0], bfr[nf][0], acc[q * 2 + mf][nf], 0, 0, 0);
          acc[q * 2 + mf][nf] = __builtin_amdgcn_mfma_f32_16x16x32_bf16(af[mf][1], bfr[nf][1], acc[q * 2 + mf][nf], 0, 0, 0);
        }
      __builtin_amdgcn_s_setprio(0);
      if (q == 3) {
        if (t0 < 14)       asm volatile("s_waitcnt vmcnt(2)" ::: "memory");
        else if (t0 == 14) asm volatile("s_waitcnt vmcnt(0)" ::: "memory");
      }
      __builtin_amdgcn_s_barrier();
      __builtin_amdgcn_sched_barrier(0);
    }
  }

  // ---- epilogue: bias add, f32->bf16, store
  const int r4 = lg * 4;
  float badd[4];
#pragma unroll
  for (int nf = 0; nf < 4; ++nf) badd[nf] = bc[bn * 256 + wcb + nf * 16 + l15];
#pragma unroll
  for (int fm = 0; fm < 8; ++fm) {
    const int row = bm * 256 + wrb + fm * 16 + r4;
#pragma unroll
    for (int nf = 0; nf < 4; ++nf) {
      const int col = bn * 256 + wcb + nf * 16 + l15;
      unsigned short* out = C + (size_t)row * N_DIM + col;
#pragma unroll
      for (int i = 0; i < 4; ++i)
        out[(size_t)i * N_DIM] = f2bf(acc[fm][nf][i] + badd[nf]);
    }
  }
#undef STAGE
#undef SB0
#undef SB1
#undef SA0
#undef SA1
#undef LDF
}

// ---------- SRU recurrence: 2 adjacent chains (d, d+1) per thread ----------
// u interleaved j=3d+k: per step one thread reads 3 dwords (12B contiguous)
// covering both chains' u0,u1,u2, plus 1 dword of x (2 bf16).
__global__ void k_rec(const unsigned short* __restrict__ xb,  // chunk (Lc, BD) bf16
                      const unsigned short* __restrict__ u3,  // chunk (Lc*32, 3072) bf16, j=3d+k
                      const float* __restrict__ wcv,
                      const float* __restrict__ sxp,
                      float* __restrict__ c_state,            // (BD)
                      float* __restrict__ h,                  // chunk base (Lc, BD) f32
                      int Lc)
{
  const int tid = blockIdx.x * 64 + threadIdx.x;   // 0..16383
  const int d = (tid & 511) * 2;                   // even d
  const int b = tid >> 9;                          // 0..31
  const int ci = b * D_DIM + d;
  const float fw0 = wcv[d],           fw1 = wcv[d + 1];
  const float rw0 = wcv[D_DIM + d],   rw1 = wcv[D_DIM + d + 1];
  const float sx = sxp[0];
  float c0 = c_state[ci], c1 = c_state[ci + 1];

  const unsigned short* up = u3 + (size_t)b * N_DIM + 3 * d;
  const unsigned short* xp = xb + ci;
  float*                hp = h + ci;

#pragma unroll 16
  for (int l = 0; l < Lc; ++l) {
    const unsigned w0 = *reinterpret_cast<const unsigned*>(up);       // u0(d), u1(d)
    const unsigned w1 = *reinterpret_cast<const unsigned*>(up + 2);   // u2(d), u0(d+1)
    const unsigned w2 = *reinterpret_cast<const unsigned*>(up + 4);   // u1(d+1), u2(d+1)
    const unsigned xw = *reinterpret_cast<const unsigned*>(xp);
    float u0a = bf2f((unsigned short)w0);
    float u1a = bf2f((unsigned short)(w0 >> 16));
    float u2a = bf2f((unsigned short)w1);
    float u0b = bf2f((unsigned short)(w1 >> 16));
    float u1b = bf2f((unsigned short)w2);
    float u2b = bf2f((unsigned short)(w2 >> 16));
    float xa = bf2f((unsigned short)xw) * sx;
    float xv = bf2f((unsigned short)(xw >> 16)) * sx;

    float f0 = 1.f / (1.f + __expf(-(u1a + c0 * fw0)));
    float r0 = 1.f / (1.f + __expf(-(u2a + c0 * rw0)));
    c0 = u0a + (c0 - u0a) * f0;
    float h0 = xa + (c0 - xa) * r0;

    float f1 = 1.f / (1.f + __expf(-(u1b + c1 * fw1)));
    float r1 = 1.f / (1.f + __expf(-(u2b + c1 * rw1)));
    c1 = u0b + (c1 - u0b) * f1;
    float h1 = xv + (c1 - xv) * r1;

    float2 st; st.x = h0; st.y = h1;
    *reinterpret_cast<float2*>(hp) = st;

    up += (size_t)32 * N_DIM;
    xp += BD;
    hp += BD;
  }
  c_state[ci] = c0;
  c_state[ci + 1] = c1;
}

__global__ void k_copyc(const float* __restrict__ c_state, float* __restrict__ out) {
  int i = blockIdx.x * blockDim.x + threadIdx.x;
  if (i < BD) out[i] = c_state[i];
}

extern "C" void kernel_launch(void* const* d_in, const int* in_sizes, int n_in,
                              void* d_out, int out_size, void* d_ws, size_t ws_size,
                              hipStream_t stream) {
  const float* x    = (const float*)d_in[0];
  const float* w    = (const float*)d_in[1];
  const float* wcv  = (const float*)d_in[2];
  const float* bias = (const float*)d_in[3];
  const float* sx   = (const float*)d_in[4];
  float* hout = (float*)d_out;
  float* cout = hout + (size_t)L_DIM * BD;

  const size_t wt_bytes  = (size_t)N_DIM * K_DIM * 2;
  const size_t bc_off    = wt_bytes;
  const size_t c_off     = bc_off + (size_t)N_DIM * 4;
  const size_t xbf_off   = c_off + (size_t)BD * 4;
  const size_t xbf_bytes = (size_t)L_DIM * BD * 2;   // full-x bf16: 134 MB
  const size_t u3_off    = xbf_off + xbf_bytes;
  int Lc = 8;
  for (int cand : {512, 256, 128, 64, 32, 16, 8}) {
    size_t need = u3_off + (size_t)cand * 196608 + 1024;   // u3 chunk bf16
    if (need <= ws_size) { Lc = cand; break; }
  }
  char* wsb = (char*)d_ws;
  unsigned short* wt_p  = (unsigned short*)wsb;
  float*          bc_p  = (float*)(wsb + bc_off);
  float*          c_p   = (float*)(wsb + c_off);
  unsigned short* xbf_p = (unsigned short*)(wsb + xbf_off);
  unsigned short* u3_p  = (unsigned short*)(wsb + u3_off);

  hipMemsetAsync(c_p, 0, (size_t)BD * 4, stream);
  k_wt<<<16 * 48, 256, 0, stream>>>(w, wt_p);
  k_biascol<<<(N_DIM + 255) / 256, 256, 0, stream>>>(bias, bc_p);
  k_convx<<<(L_DIM * BD / 8) / 256, 256, 0, stream>>>(x, xbf_p, L_DIM * BD / 8);

  const int nchunks = L_DIM / Lc;
  const int Mtiles  = (Lc * B_DIM) / 256;
  for (int ci = 0; ci < nchunks; ++ci) {
    const size_t base = (size_t)ci * Lc * BD;
    k_gemm<<<Mtiles * (N_DIM / 256), 512, 0, stream>>>(xbf_p + base, wt_p, bc_p, u3_p, Mtiles);
    k_rec<<<BD / 128, 64, 0, stream>>>(xbf_p + base, u3_p, wcv, sx, c_p, hout + base, Lc);
  }
  k_copyc<<<BD / 256, 256, 0, stream>>>(c_p, cout);
}

// Round 11
// 968.110 us; speedup vs baseline: 2.0900x; 1.4757x over previous
//
#include <hip/hip_runtime.h>
#include <stdint.h>

#define L_DIM 2048
#define B_DIM 32
#define D_DIM 1024
#define N_DIM 3072   // 3*D
#define K_DIM 1024
#define BD    32768  // B*D
#define S3    (32 * N_DIM)   // u3 step stride (ushorts)

typedef __bf16 bf16x8 __attribute__((ext_vector_type(8)));
typedef unsigned short ushort8 __attribute__((ext_vector_type(8)));
typedef float f32x4 __attribute__((ext_vector_type(4)));

typedef const __attribute__((address_space(1))) unsigned int* gq_t;
typedef __attribute__((address_space(3))) unsigned int* lq_t;

static __device__ __forceinline__ unsigned short f2bf(float f) {
  unsigned u = __float_as_uint(f);
  u += 0x7FFFu + ((u >> 16) & 1u);   // RNE
  return (unsigned short)(u >> 16);
}

static __device__ __forceinline__ float bf2f(unsigned short s) {
  return __uint_as_float(((unsigned)s) << 16);
}

// ---------- convert ALL of x (f32) -> bf16, 8 elems/thread, one pass ----------
__global__ void k_convx(const float* __restrict__ x, unsigned short* __restrict__ xb, int n8) {
  int i = blockIdx.x * blockDim.x + threadIdx.x;
  if (i >= n8) return;
  const float4* p = reinterpret_cast<const float4*>(x) + (size_t)i * 2;
  float4 a = p[0], b = p[1];
  ushort8 o;
  o[0] = f2bf(a.x); o[1] = f2bf(a.y); o[2] = f2bf(a.z); o[3] = f2bf(a.w);
  o[4] = f2bf(b.x); o[5] = f2bf(b.y); o[6] = f2bf(b.z); o[7] = f2bf(b.w);
  reinterpret_cast<ushort8*>(xb)[i] = o;
}

// ---------- W (K, N=3072 cols j=3d+k) f32 -> WT (N, K) bf16, straight transpose ----------
__global__ __launch_bounds__(256) void k_wt(const float* __restrict__ w, unsigned short* __restrict__ wt) {
  __shared__ unsigned short tile[64][65];
  const int kb = blockIdx.x & 15;        // K/64 tile
  const int nb = blockIdx.x >> 4;        // N/64 tile 0..47
  const int t = threadIdx.x;
  const int c = t & 63;
  const int q = t >> 6;                  // 0..3
#pragma unroll
  for (int i = 0; i < 16; ++i) {
    int r = q * 16 + i;                  // k within tile
    tile[r][c] = f2bf(w[(size_t)(kb * 64 + r) * N_DIM + nb * 64 + c]);
  }
  __syncthreads();
  const int k = t & 63;
#pragma unroll
  for (int i = 0; i < 16; ++i) {
    int n = q * 16 + i;                  // n within tile
    wt[(size_t)(nb * 64 + n) * K_DIM + kb * 64 + k] = tile[k][n];
  }
}

// ---------- per-column bias, interleaved layout: col j = 3d+k ----------
__global__ void k_biascol(const float* __restrict__ bias, float* __restrict__ bc) {
  int j = blockIdx.x * blockDim.x + threadIdx.x;
  if (j >= N_DIM) return;
  int d = j / 3;
  int k = j - 3 * d;
  float v = 0.f;
  if (k == 1) v = bias[d];
  else if (k == 2) v = bias[D_DIM + d];
  bc[j] = v;
}

// ---------- 256x256 8-phase bf16 MFMA GEMM (T1+T2+T3+T4+T5), bn-fast ----------
__global__ __launch_bounds__(512, 2) void k_gemm(
    const unsigned short* __restrict__ A,
    const unsigned short* __restrict__ BT,
    const float* __restrict__ bc,
    unsigned short* __restrict__ C,
    int Mtiles)
{
  __shared__ unsigned short smem[65536];

  // --- block swizzle (bijective, 8 XCDs); bn fast so same-XCD neighbors share A panel
  const int nwg = gridDim.x;
  const int q8 = nwg >> 3, r8 = nwg & 7;
  const int xcd = blockIdx.x & 7, li = blockIdx.x >> 3;
  const int wg = (xcd < r8 ? xcd * (q8 + 1) : r8 * (q8 + 1) + (xcd - r8) * q8) + li;
  const int NT = N_DIM / 256;   // 12
  const int bn = wg % NT;
  const int bm = wg / NT;

  const int t  = threadIdx.x;
  const int w  = t >> 6;
  const int l  = t & 63;
  const int wr = w >> 2, wc = w & 3;
  const int wrb = wr * 128, wcb = wc * 64;
  const int l15 = l & 15, lg = l >> 4, lx = l & 7;
  const int kgp0 = (lg ^ lx) * 8;          // elem offset of ksub=0 octet
  const int kgp1 = ((4 + lg) ^ lx) * 8;    // ksub=1
  const int sr0 = w * 8 + (l >> 3);        // staging row within half
  const int kgs = (lx ^ (l >> 3)) * 8;     // swizzled source k-octet

  const unsigned short* Abase = A  + (size_t)(bm * 256) * K_DIM;
  const unsigned short* Bbase = BT + (size_t)(bn * 256) * K_DIM;

  f32x4 acc[8][4];
#pragma unroll
  for (int i = 0; i < 8; ++i)
#pragma unroll
    for (int j = 0; j < 4; ++j) acc[i][j] = f32x4{0.f, 0.f, 0.f, 0.f};

#define STAGE(G, growbase, T, ldsBase)                                                  \
  { const unsigned short* s0_ = (G) + (((size_t)((growbase) + sr0)) << 10) + (T) * 64 + kgs; \
    __builtin_amdgcn_global_load_lds((gq_t)s0_, (lq_t)&smem[(ldsBase) + w * 512], 16, 0, 0); \
    const unsigned short* s1_ = s0_ + (64 << 10);                                       \
    __builtin_amdgcn_global_load_lds((gq_t)s1_, (lq_t)&smem[(ldsBase) + 4096 + w * 512], 16, 0, 0); }

#define SB0(T, b) STAGE(Bbase, 0,   (T), (b) * 32768 + 16384)
#define SB1(T, b) STAGE(Bbase, 128, (T), (b) * 32768 + 16384 + 8192)
#define SA0(T, b) STAGE(Abase, 0,   (T), (b) * 32768)
#define SA1(T, b) STAGE(Abase, 128, (T), (b) * 32768 + 8192)

#define LDF(idx) __builtin_bit_cast(bf16x8, *reinterpret_cast<const ushort8*>(&smem[(idx)]))

  // ---- prologue: tile0 fully + SB0(1); wait tile0, SB0(1) stays in flight
  SB0(0, 0); SB1(0, 0); SA0(0, 0); SA1(0, 0); SB0(1, 1);
  asm volatile("s_waitcnt vmcnt(2)" ::: "memory");
  __builtin_amdgcn_s_barrier();

#pragma unroll 2
  for (int t0 = 0; t0 < 16; ++t0) {
    const int cur = t0 & 1, nxt = cur ^ 1;
    const int cA = cur * 32768, cB = cA + 16384;
    bf16x8 bfr[4][2];
#pragma unroll
    for (int q = 0; q < 4; ++q) {
      bf16x8 af[2][2];
      if (q == 0) {
#pragma unroll
        for (int nf = 0; nf < 4; ++nf) {
          const int nr = (wcb + nf * 16 + l15) * 64;
          bfr[nf][0] = LDF(cB + nr + kgp0);
          bfr[nf][1] = LDF(cB + nr + kgp1);
        }
      }
#pragma unroll
      for (int mf = 0; mf < 2; ++mf) {
        const int ar = (wrb + (q * 2 + mf) * 16 + l15) * 64;
        af[mf][0] = LDF(cA + ar + kgp0);
        af[mf][1] = LDF(cA + ar + kgp1);
      }
      if (q == 0 && t0 < 15) SB1(t0 + 1, nxt);
      if (q == 1 && t0 < 15) SA0(t0 + 1, nxt);
      if (q == 2 && t0 < 15) SA1(t0 + 1, nxt);
      if (q == 3 && t0 < 14) SB0(t0 + 2, cur);

      __builtin_amdgcn_s_barrier();
      __builtin_amdgcn_s_setprio(1);
#pragma unroll
      for (int mf = 0; mf < 2; ++mf)
#pragma unroll
        for (int nf = 0; nf < 4; ++nf) {
          acc[q * 2 + mf][nf] = __builtin_amdgcn_mfma_f32_16x16x32_bf16(af[mf][0], bfr[nf][0], acc[q * 2 + mf][nf], 0, 0, 0);
          acc[q * 2 + mf][nf] = __builtin_amdgcn_mfma_f32_16x16x32_bf16(af[mf][1], bfr[nf][1], acc[q * 2 + mf][nf], 0, 0, 0);
        }
      __builtin_amdgcn_s_setprio(0);
      if (q == 3) {
        if (t0 < 14)       asm volatile("s_waitcnt vmcnt(2)" ::: "memory");
        else if (t0 == 14) asm volatile("s_waitcnt vmcnt(0)" ::: "memory");
      }
      __builtin_amdgcn_s_barrier();
      __builtin_amdgcn_sched_barrier(0);
    }
  }

  // ---- epilogue: bias add, f32->bf16, store
  const int r4 = lg * 4;
  float badd[4];
#pragma unroll
  for (int nf = 0; nf < 4; ++nf) badd[nf] = bc[bn * 256 + wcb + nf * 16 + l15];
#pragma unroll
  for (int fm = 0; fm < 8; ++fm) {
    const int row = bm * 256 + wrb + fm * 16 + r4;
#pragma unroll
    for (int nf = 0; nf < 4; ++nf) {
      const int col = bn * 256 + wcb + nf * 16 + l15;
      unsigned short* out = C + (size_t)row * N_DIM + col;
#pragma unroll
      for (int i = 0; i < 4; ++i)
        out[(size_t)i * N_DIM] = f2bf(acc[fm][nf][i] + badd[nf]);
    }
  }
#undef STAGE
#undef SB0
#undef SB1
#undef SA0
#undef SA1
#undef LDF
}

// ---------- SRU recurrence: LDS-ring async-staged scan ----------
// 1 wave/block, 128 chains/block (2 per thread). Ring: 32 slots x 1KB LDS,
// depth-16 global_load_lds pipeline; in-flight bytes live in LDS, not VGPRs.
// Per step ONE staging instr: lanes 0-47 fetch 768B of u3, lanes 48-63 256B of x.
__global__ void k_rec(const unsigned short* __restrict__ xb,  // chunk (Lc, BD) bf16
                      const unsigned short* __restrict__ u3,  // chunk (Lc*32, 3072) bf16, j=3d+k
                      const float* __restrict__ wcv,
                      const float* __restrict__ sxp,
                      float* __restrict__ c_state,            // (BD)
                      float* __restrict__ h,                  // chunk base (Lc, BD) f32
                      int Lc)
{
  __shared__ unsigned int lds_u32[32 * 256];   // 32 slots x 1024 B

  const int ln = threadIdx.x;                  // lane 0..63
  const int bi = blockIdx.x;                   // 0..255
  const int b  = bi >> 3;                      // batch 0..31
  const int d0 = (bi & 7) * 128;               // chain base within batch
  const int d  = d0 + 2 * ln;
  const int ci = b * D_DIM + d;

  const float fw0 = wcv[d],         fw1 = wcv[d + 1];
  const float rw0 = wcv[D_DIM + d], rw1 = wcv[D_DIM + d + 1];
  const float sx = sxp[0];
  float c0 = c_state[ci], c1 = c_state[ci + 1];

  const int ub_off = b * N_DIM + 3 * d0;       // ushort offset of block's u3 slice in a step row
  const int xw_off = b * D_DIM + d0;           // ushort offset of block's x slice

#define RSTAGE(ls)                                                                       \
  { const int slot_ = (ls) & 31;                                                         \
    const unsigned short* us_ = u3 + (size_t)(ls) * S3 + ub_off + ln * 8;                \
    const unsigned short* xs_ = xb + (size_t)(ls) * BD + xw_off + (ln - 48) * 8;         \
    const unsigned short* src_ = (ln < 48) ? us_ : xs_;                                  \
    __builtin_amdgcn_global_load_lds((gq_t)src_, (lq_t)(lds_u32 + slot_ * 256), 16, 0, 0); }

  // prologue: fill pipeline with 16 steps
#pragma unroll
  for (int i = 0; i < 16; ++i) RSTAGE(i)

  float* hp = h + ci;
#pragma unroll 4
  for (int l = 0; l < Lc; ++l) {
    asm volatile("s_waitcnt vmcnt(15)" ::: "memory");   // step l landed in LDS
    const int ls = (l + 16 < Lc) ? (l + 16) : (l + 16 - Lc);  // wrap: harmless L2-hot re-stage
    RSTAGE(ls)
    __builtin_amdgcn_sched_barrier(0);

    const int sb = (l & 31) * 256;
    const unsigned w0 = lds_u32[sb + ln * 3 + 0];   // u0(d), u1(d)
    const unsigned w1 = lds_u32[sb + ln * 3 + 1];   // u2(d), u0(d+1)
    const unsigned w2 = lds_u32[sb + ln * 3 + 2];   // u1(d+1), u2(d+1)
    const unsigned xw = lds_u32[sb + 192 + ln];     // x(d), x(d+1)

    float u0a = bf2f((unsigned short)w0);
    float u1a = bf2f((unsigned short)(w0 >> 16));
    float u2a = bf2f((unsigned short)w1);
    float u0b = bf2f((unsigned short)(w1 >> 16));
    float u1b = bf2f((unsigned short)w2);
    float u2b = bf2f((unsigned short)(w2 >> 16));
    float xa = bf2f((unsigned short)xw) * sx;
    float xv = bf2f((unsigned short)(xw >> 16)) * sx;

    float f0 = 1.f / (1.f + __expf(-(u1a + c0 * fw0)));
    float r0 = 1.f / (1.f + __expf(-(u2a + c0 * rw0)));
    c0 = u0a + (c0 - u0a) * f0;
    float h0 = xa + (c0 - xa) * r0;

    float f1 = 1.f / (1.f + __expf(-(u1b + c1 * fw1)));
    float r1 = 1.f / (1.f + __expf(-(u2b + c1 * rw1)));
    c1 = u0b + (c1 - u0b) * f1;
    float h1 = xv + (c1 - xv) * r1;

    float2 st; st.x = h0; st.y = h1;
    *reinterpret_cast<float2*>(hp) = st;
    hp += BD;
  }
  c_state[ci] = c0;
  c_state[ci + 1] = c1;
#undef RSTAGE
}

__global__ void k_copyc(const float* __restrict__ c_state, float* __restrict__ out) {
  int i = blockIdx.x * blockDim.x + threadIdx.x;
  if (i < BD) out[i] = c_state[i];
}

extern "C" void kernel_launch(void* const* d_in, const int* in_sizes, int n_in,
                              void* d_out, int out_size, void* d_ws, size_t ws_size,
                              hipStream_t stream) {
  const float* x    = (const float*)d_in[0];
  const float* w    = (const float*)d_in[1];
  const float* wcv  = (const float*)d_in[2];
  const float* bias = (const float*)d_in[3];
  const float* sx   = (const float*)d_in[4];
  float* hout = (float*)d_out;
  float* cout = hout + (size_t)L_DIM * BD;

  const size_t wt_bytes  = (size_t)N_DIM * K_DIM * 2;
  const size_t bc_off    = wt_bytes;
  const size_t c_off     = bc_off + (size_t)N_DIM * 4;
  const size_t xbf_off   = c_off + (size_t)BD * 4;
  const size_t xbf_bytes = (size_t)L_DIM * BD * 2;   // full-x bf16: 134 MB
  const size_t u3_off    = xbf_off + xbf_bytes;
  int Lc = 8;
  for (int cand : {512, 256, 128, 64, 32, 16, 8}) {
    size_t need = u3_off + (size_t)cand * 196608 + 1024;   // u3 chunk bf16
    if (need <= ws_size) { Lc = cand; break; }
  }
  char* wsb = (char*)d_ws;
  unsigned short* wt_p  = (unsigned short*)wsb;
  float*          bc_p  = (float*)(wsb + bc_off);
  float*          c_p   = (float*)(wsb + c_off);
  unsigned short* xbf_p = (unsigned short*)(wsb + xbf_off);
  unsigned short* u3_p  = (unsigned short*)(wsb + u3_off);

  hipMemsetAsync(c_p, 0, (size_t)BD * 4, stream);
  k_wt<<<16 * 48, 256, 0, stream>>>(w, wt_p);
  k_biascol<<<(N_DIM + 255) / 256, 256, 0, stream>>>(bias, bc_p);
  k_convx<<<(L_DIM * BD / 8) / 256, 256, 0, stream>>>(x, xbf_p, L_DIM * BD / 8);

  const int nchunks = L_DIM / Lc;
  const int Mtiles  = (Lc * B_DIM) / 256;
  for (int ci = 0; ci < nchunks; ++ci) {
    const size_t base = (size_t)ci * Lc * BD;
    k_gemm<<<Mtiles * (N_DIM / 256), 512, 0, stream>>>(xbf_p + base, wt_p, bc_p, u3_p, Mtiles);
    k_rec<<<BD / 128, 64, 0, stream>>>(xbf_p + base, u3_p, wcv, sx, c_p, hout + base, Lc);
  }
  k_copyc<<<BD / 256, 256, 0, stream>>>(c_p, cout);
}

// Round 12
// 941.555 us; speedup vs baseline: 2.1489x; 1.0282x over previous
//
#include <hip/hip_runtime.h>
#include <stdint.h>

#define L_DIM 2048
#define B_DIM 32
#define D_DIM 1024
#define N_DIM 3072   // 3*D
#define K_DIM 1024
#define BD    32768  // B*D
#define S3    (32 * N_DIM)   // u3 step stride (ushorts)

typedef __bf16 bf16x8 __attribute__((ext_vector_type(8)));
typedef unsigned short ushort8 __attribute__((ext_vector_type(8)));
typedef float f32x4 __attribute__((ext_vector_type(4)));

typedef const __attribute__((address_space(1))) unsigned int* gq_t;
typedef __attribute__((address_space(3))) unsigned int* lq_t;

static __device__ __forceinline__ unsigned short f2bf(float f) {
  unsigned u = __float_as_uint(f);
  u += 0x7FFFu + ((u >> 16) & 1u);   // RNE
  return (unsigned short)(u >> 16);
}

static __device__ __forceinline__ float bf2f(unsigned short s) {
  return __uint_as_float(((unsigned)s) << 16);
}

// ---------- convert ALL of x (f32) -> bf16, 8 elems/thread, one pass ----------
__global__ void k_convx(const float* __restrict__ x, unsigned short* __restrict__ xb, int n8) {
  int i = blockIdx.x * blockDim.x + threadIdx.x;
  if (i >= n8) return;
  const float4* p = reinterpret_cast<const float4*>(x) + (size_t)i * 2;
  float4 a = p[0], b = p[1];
  ushort8 o;
  o[0] = f2bf(a.x); o[1] = f2bf(a.y); o[2] = f2bf(a.z); o[3] = f2bf(a.w);
  o[4] = f2bf(b.x); o[5] = f2bf(b.y); o[6] = f2bf(b.z); o[7] = f2bf(b.w);
  reinterpret_cast<ushort8*>(xb)[i] = o;
}

// ---------- W (K, N=3072 cols j=3d+k) f32 -> WT (N, K) bf16, straight transpose ----------
__global__ __launch_bounds__(256) void k_wt(const float* __restrict__ w, unsigned short* __restrict__ wt) {
  __shared__ unsigned short tile[64][65];
  const int kb = blockIdx.x & 15;        // K/64 tile
  const int nb = blockIdx.x >> 4;        // N/64 tile 0..47
  const int t = threadIdx.x;
  const int c = t & 63;
  const int q = t >> 6;                  // 0..3
#pragma unroll
  for (int i = 0; i < 16; ++i) {
    int r = q * 16 + i;                  // k within tile
    tile[r][c] = f2bf(w[(size_t)(kb * 64 + r) * N_DIM + nb * 64 + c]);
  }
  __syncthreads();
  const int k = t & 63;
#pragma unroll
  for (int i = 0; i < 16; ++i) {
    int n = q * 16 + i;                  // n within tile
    wt[(size_t)(nb * 64 + n) * K_DIM + kb * 64 + k] = tile[k][n];
  }
}

// ---------- per-column bias, interleaved layout: col j = 3d+k ----------
__global__ void k_biascol(const float* __restrict__ bias, float* __restrict__ bc) {
  int j = blockIdx.x * blockDim.x + threadIdx.x;
  if (j >= N_DIM) return;
  int d = j / 3;
  int k = j - 3 * d;
  float v = 0.f;
  if (k == 1) v = bias[d];
  else if (k == 2) v = bias[D_DIM + d];
  bc[j] = v;
}

// ---------- 256x256 8-phase bf16 MFMA GEMM (T1+T2+T3+T4+T5), bn-fast ----------
__global__ __launch_bounds__(512, 2) void k_gemm(
    const unsigned short* __restrict__ A,
    const unsigned short* __restrict__ BT,
    const float* __restrict__ bc,
    unsigned short* __restrict__ C,
    int Mtiles)
{
  __shared__ unsigned short smem[65536];

  // --- block swizzle (bijective, 8 XCDs); bn fast so same-XCD neighbors share A panel
  const int nwg = gridDim.x;
  const int q8 = nwg >> 3, r8 = nwg & 7;
  const int xcd = blockIdx.x & 7, li = blockIdx.x >> 3;
  const int wg = (xcd < r8 ? xcd * (q8 + 1) : r8 * (q8 + 1) + (xcd - r8) * q8) + li;
  const int NT = N_DIM / 256;   // 12
  const int bn = wg % NT;
  const int bm = wg / NT;

  const int t  = threadIdx.x;
  const int w  = t >> 6;
  const int l  = t & 63;
  const int wr = w >> 2, wc = w & 3;
  const int wrb = wr * 128, wcb = wc * 64;
  const int l15 = l & 15, lg = l >> 4, lx = l & 7;
  const int kgp0 = (lg ^ lx) * 8;          // elem offset of ksub=0 octet
  const int kgp1 = ((4 + lg) ^ lx) * 8;    // ksub=1
  const int sr0 = w * 8 + (l >> 3);        // staging row within half
  const int kgs = (lx ^ (l >> 3)) * 8;     // swizzled source k-octet

  const unsigned short* Abase = A  + (size_t)(bm * 256) * K_DIM;
  const unsigned short* Bbase = BT + (size_t)(bn * 256) * K_DIM;

  f32x4 acc[8][4];
#pragma unroll
  for (int i = 0; i < 8; ++i)
#pragma unroll
    for (int j = 0; j < 4; ++j) acc[i][j] = f32x4{0.f, 0.f, 0.f, 0.f};

#define STAGE(G, growbase, T, ldsBase)                                                  \
  { const unsigned short* s0_ = (G) + (((size_t)((growbase) + sr0)) << 10) + (T) * 64 + kgs; \
    __builtin_amdgcn_global_load_lds((gq_t)s0_, (lq_t)&smem[(ldsBase) + w * 512], 16, 0, 0); \
    const unsigned short* s1_ = s0_ + (64 << 10);                                       \
    __builtin_amdgcn_global_load_lds((gq_t)s1_, (lq_t)&smem[(ldsBase) + 4096 + w * 512], 16, 0, 0); }

#define SB0(T, b) STAGE(Bbase, 0,   (T), (b) * 32768 + 16384)
#define SB1(T, b) STAGE(Bbase, 128, (T), (b) * 32768 + 16384 + 8192)
#define SA0(T, b) STAGE(Abase, 0,   (T), (b) * 32768)
#define SA1(T, b) STAGE(Abase, 128, (T), (b) * 32768 + 8192)

#define LDF(idx) __builtin_bit_cast(bf16x8, *reinterpret_cast<const ushort8*>(&smem[(idx)]))

  // ---- prologue: tile0 fully + SB0(1); wait tile0, SB0(1) stays in flight
  SB0(0, 0); SB1(0, 0); SA0(0, 0); SA1(0, 0); SB0(1, 1);
  asm volatile("s_waitcnt vmcnt(2)" ::: "memory");
  __builtin_amdgcn_s_barrier();

#pragma unroll 2
  for (int t0 = 0; t0 < 16; ++t0) {
    const int cur = t0 & 1, nxt = cur ^ 1;
    const int cA = cur * 32768, cB = cA + 16384;
    bf16x8 bfr[4][2];
#pragma unroll
    for (int q = 0; q < 4; ++q) {
      bf16x8 af[2][2];
      if (q == 0) {
#pragma unroll
        for (int nf = 0; nf < 4; ++nf) {
          const int nr = (wcb + nf * 16 + l15) * 64;
          bfr[nf][0] = LDF(cB + nr + kgp0);
          bfr[nf][1] = LDF(cB + nr + kgp1);
        }
      }
#pragma unroll
      for (int mf = 0; mf < 2; ++mf) {
        const int ar = (wrb + (q * 2 + mf) * 16 + l15) * 64;
        af[mf][0] = LDF(cA + ar + kgp0);
        af[mf][1] = LDF(cA + ar + kgp1);
      }
      if (q == 0 && t0 < 15) SB1(t0 + 1, nxt);
      if (q == 1 && t0 < 15) SA0(t0 + 1, nxt);
      if (q == 2 && t0 < 15) SA1(t0 + 1, nxt);
      if (q == 3 && t0 < 14) SB0(t0 + 2, cur);

      __builtin_amdgcn_s_barrier();
      __builtin_amdgcn_s_setprio(1);
#pragma unroll
      for (int mf = 0; mf < 2; ++mf)
#pragma unroll
        for (int nf = 0; nf < 4; ++nf) {
          acc[q * 2 + mf][nf] = __builtin_amdgcn_mfma_f32_16x16x32_bf16(af[mf][0], bfr[nf][0], acc[q * 2 + mf][nf], 0, 0, 0);
          acc[q * 2 + mf][nf] = __builtin_amdgcn_mfma_f32_16x16x32_bf16(af[mf][1], bfr[nf][1], acc[q * 2 + mf][nf], 0, 0, 0);
        }
      __builtin_amdgcn_s_setprio(0);
      if (q == 3) {
        if (t0 < 14)       asm volatile("s_waitcnt vmcnt(2)" ::: "memory");
        else if (t0 == 14) asm volatile("s_waitcnt vmcnt(0)" ::: "memory");
      }
      __builtin_amdgcn_s_barrier();
      __builtin_amdgcn_sched_barrier(0);
    }
  }

  // ---- epilogue: bias add, f32->bf16, store
  const int r4 = lg * 4;
  float badd[4];
#pragma unroll
  for (int nf = 0; nf < 4; ++nf) badd[nf] = bc[bn * 256 + wcb + nf * 16 + l15];
#pragma unroll
  for (int fm = 0; fm < 8; ++fm) {
    const int row = bm * 256 + wrb + fm * 16 + r4;
#pragma unroll
    for (int nf = 0; nf < 4; ++nf) {
      const int col = bn * 256 + wcb + nf * 16 + l15;
      unsigned short* out = C + (size_t)row * N_DIM + col;
#pragma unroll
      for (int i = 0; i < 4; ++i)
        out[(size_t)i * N_DIM] = f2bf(acc[fm][nf][i] + badd[nf]);
    }
  }
#undef STAGE
#undef SB0
#undef SB1
#undef SA0
#undef SA1
#undef LDF
}

// ---------- SRU recurrence: LDS-ring async scan + reg double-buffer ----------
// 1 wave/block, 128 chains/block (2/thread). Ring: 32 slots x 1KB LDS, depth-16
// global_load_lds. Per iter: stage(l+16) -> vmcnt(15) [step l+1 landed] ->
// ds_read slot l+1 into NEXT regs (latency hides under compute of step l).
__global__ __launch_bounds__(64) void k_rec(
    const unsigned short* __restrict__ xb,  // chunk (Lc, BD) bf16
    const unsigned short* __restrict__ u3,  // chunk (Lc*32, 3072) bf16, j=3d+k
    const float* __restrict__ wcv,
    const float* __restrict__ sxp,
    float* __restrict__ c_state,            // (BD)
    float* __restrict__ h,                  // chunk base (Lc, BD) f32
    int Lc)
{
  __shared__ unsigned int lds_u32[32 * 256];   // 32 slots x 1024 B

  const int ln = threadIdx.x;                  // lane 0..63
  const int bi = blockIdx.x;                   // 0..255
  const int b  = bi >> 3;                      // batch 0..31
  const int d0 = (bi & 7) * 128;               // chain base within batch
  const int d  = d0 + 2 * ln;
  const int ci = b * D_DIM + d;

  const float fw0 = wcv[d],         fw1 = wcv[d + 1];
  const float rw0 = wcv[D_DIM + d], rw1 = wcv[D_DIM + d + 1];
  const float sx = sxp[0];
  float c0 = c_state[ci], c1 = c_state[ci + 1];

  const int ub_off = b * N_DIM + 3 * d0;       // ushort offset of block's u3 slice in a step row
  const int xw_off = b * D_DIM + d0;           // ushort offset of block's x slice

#define RSTAGE(ls)                                                                       \
  { const int slot_ = (ls) & 31;                                                         \
    const unsigned short* us_ = u3 + (size_t)(ls) * S3 + ub_off + ln * 8;                \
    const unsigned short* xs_ = xb + (size_t)(ls) * BD + xw_off + (ln - 48) * 8;         \
    const unsigned short* src_ = (ln < 48) ? us_ : xs_;                                  \
    __builtin_amdgcn_global_load_lds((gq_t)src_, (lq_t)(lds_u32 + slot_ * 256), 16, 0, 0); }

  // prologue: fill pipeline with 16 steps, then pull step 0 into registers
#pragma unroll
  for (int i = 0; i < 16; ++i) RSTAGE(i)
  asm volatile("s_waitcnt vmcnt(15)" ::: "memory");   // step 0 landed
  unsigned cw0 = lds_u32[ln * 3 + 0];
  unsigned cw1 = lds_u32[ln * 3 + 1];
  unsigned cw2 = lds_u32[ln * 3 + 2];
  unsigned cxw = lds_u32[192 + ln];

  float* hp = h + ci;
#pragma unroll 4
  for (int l = 0; l < Lc; ++l) {
    const int ls = (l + 16 < Lc) ? (l + 16) : (l + 16 - Lc);  // wrap: harmless L2-hot re-stage
    RSTAGE(ls)
    asm volatile("s_waitcnt vmcnt(15)" ::: "memory");   // step l+1 landed in LDS

    // prefetch step l+1 into regs; consumed next iteration (latency hidden)
    const int nsb = ((l + 1) & 31) * 256;
    const unsigned nw0 = lds_u32[nsb + ln * 3 + 0];
    const unsigned nw1 = lds_u32[nsb + ln * 3 + 1];
    const unsigned nw2 = lds_u32[nsb + ln * 3 + 2];
    const unsigned nxw = lds_u32[nsb + 192 + ln];

    // compute step l from current regs
    float u0a = bf2f((unsigned short)cw0);
    float u1a = bf2f((unsigned short)(cw0 >> 16));
    float u2a = bf2f((unsigned short)cw1);
    float u0b = bf2f((unsigned short)(cw1 >> 16));
    float u1b = bf2f((unsigned short)cw2);
    float u2b = bf2f((unsigned short)(cw2 >> 16));
    float xa = bf2f((unsigned short)cxw) * sx;
    float xv = bf2f((unsigned short)(cxw >> 16)) * sx;

    float f0 = 1.f / (1.f + __expf(-(u1a + c0 * fw0)));
    float r0 = 1.f / (1.f + __expf(-(u2a + c0 * rw0)));
    c0 = u0a + (c0 - u0a) * f0;
    float h0 = xa + (c0 - xa) * r0;

    float f1 = 1.f / (1.f + __expf(-(u1b + c1 * fw1)));
    float r1 = 1.f / (1.f + __expf(-(u2b + c1 * rw1)));
    c1 = u0b + (c1 - u0b) * f1;
    float h1 = xv + (c1 - xv) * r1;

    float2 st; st.x = h0; st.y = h1;
    *reinterpret_cast<float2*>(hp) = st;
    hp += BD;

    cw0 = nw0; cw1 = nw1; cw2 = nw2; cxw = nxw;
  }
  c_state[ci] = c0;
  c_state[ci + 1] = c1;
#undef RSTAGE
}

__global__ void k_copyc(const float* __restrict__ c_state, float* __restrict__ out) {
  int i = blockIdx.x * blockDim.x + threadIdx.x;
  if (i < BD) out[i] = c_state[i];
}

extern "C" void kernel_launch(void* const* d_in, const int* in_sizes, int n_in,
                              void* d_out, int out_size, void* d_ws, size_t ws_size,
                              hipStream_t stream) {
  const float* x    = (const float*)d_in[0];
  const float* w    = (const float*)d_in[1];
  const float* wcv  = (const float*)d_in[2];
  const float* bias = (const float*)d_in[3];
  const float* sx   = (const float*)d_in[4];
  float* hout = (float*)d_out;
  float* cout = hout + (size_t)L_DIM * BD;

  const size_t wt_bytes  = (size_t)N_DIM * K_DIM * 2;
  const size_t bc_off    = wt_bytes;
  const size_t c_off     = bc_off + (size_t)N_DIM * 4;
  const size_t xbf_off   = c_off + (size_t)BD * 4;
  const size_t xbf_bytes = (size_t)L_DIM * BD * 2;   // full-x bf16: 134 MB
  const size_t u3_off    = xbf_off + xbf_bytes;
  int Lc = 8;
  for (int cand : {512, 256, 128, 64, 32, 16, 8}) {
    size_t need = u3_off + (size_t)cand * 196608 + 1024;   // u3 chunk bf16
    if (need <= ws_size) { Lc = cand; break; }
  }
  char* wsb = (char*)d_ws;
  unsigned short* wt_p  = (unsigned short*)wsb;
  float*          bc_p  = (float*)(wsb + bc_off);
  float*          c_p   = (float*)(wsb + c_off);
  unsigned short* xbf_p = (unsigned short*)(wsb + xbf_off);
  unsigned short* u3_p  = (unsigned short*)(wsb + u3_off);

  hipMemsetAsync(c_p, 0, (size_t)BD * 4, stream);
  k_wt<<<16 * 48, 256, 0, stream>>>(w, wt_p);
  k_biascol<<<(N_DIM + 255) / 256, 256, 0, stream>>>(bias, bc_p);
  k_convx<<<(L_DIM * BD / 8) / 256, 256, 0, stream>>>(x, xbf_p, L_DIM * BD / 8);

  const int nchunks = L_DIM / Lc;
  const int Mtiles  = (Lc * B_DIM) / 256;
  for (int ci = 0; ci < nchunks; ++ci) {
    const size_t base = (size_t)ci * Lc * BD;
    k_gemm<<<Mtiles * (N_DIM / 256), 512, 0, stream>>>(xbf_p + base, wt_p, bc_p, u3_p, Mtiles);
    k_rec<<<BD / 128, 64, 0, stream>>>(xbf_p + base, u3_p, wcv, sx, c_p, hout + base, Lc);
  }
  k_copyc<<<BD / 256, 256, 0, stream>>>(c_p, cout);
}

// Round 13
// 906.533 us; speedup vs baseline: 2.2319x; 1.0386x over previous
//
#include <hip/hip_runtime.h>
#include <stdint.h>

#define L_DIM 2048
#define B_DIM 32
#define D_DIM 1024
#define N_DIM 3072   // 3*D
#define K_DIM 1024
#define BD    32768  // B*D
#define S3    (32 * N_DIM)   // u3 step stride (ushorts)

typedef __bf16 bf16x8 __attribute__((ext_vector_type(8)));
typedef unsigned short ushort8 __attribute__((ext_vector_type(8)));
typedef float f32x4 __attribute__((ext_vector_type(4)));

typedef const __attribute__((address_space(1))) unsigned int* gq_t;
typedef __attribute__((address_space(3))) unsigned int* lq_t;

static __device__ __forceinline__ unsigned short f2bf(float f) {
  unsigned u = __float_as_uint(f);
  u += 0x7FFFu + ((u >> 16) & 1u);   // RNE
  return (unsigned short)(u >> 16);
}

static __device__ __forceinline__ float bf2f(unsigned short s) {
  return __uint_as_float(((unsigned)s) << 16);
}

// ---------- convert ALL of x (f32) -> bf16, 8 elems/thread, one pass ----------
__global__ void k_convx(const float* __restrict__ x, unsigned short* __restrict__ xb, int n8) {
  int i = blockIdx.x * blockDim.x + threadIdx.x;
  if (i >= n8) return;
  const float4* p = reinterpret_cast<const float4*>(x) + (size_t)i * 2;
  float4 a = p[0], b = p[1];
  ushort8 o;
  o[0] = f2bf(a.x); o[1] = f2bf(a.y); o[2] = f2bf(a.z); o[3] = f2bf(a.w);
  o[4] = f2bf(b.x); o[5] = f2bf(b.y); o[6] = f2bf(b.z); o[7] = f2bf(b.w);
  reinterpret_cast<ushort8*>(xb)[i] = o;
}

// ---------- W (K, N=3072 cols j=3d+k) f32 -> WT (N, K) bf16, straight transpose ----------
__global__ __launch_bounds__(256) void k_wt(const float* __restrict__ w, unsigned short* __restrict__ wt) {
  __shared__ unsigned short tile[64][65];
  const int kb = blockIdx.x & 15;        // K/64 tile
  const int nb = blockIdx.x >> 4;        // N/64 tile 0..47
  const int t = threadIdx.x;
  const int c = t & 63;
  const int q = t >> 6;                  // 0..3
#pragma unroll
  for (int i = 0; i < 16; ++i) {
    int r = q * 16 + i;                  // k within tile
    tile[r][c] = f2bf(w[(size_t)(kb * 64 + r) * N_DIM + nb * 64 + c]);
  }
  __syncthreads();
  const int k = t & 63;
#pragma unroll
  for (int i = 0; i < 16; ++i) {
    int n = q * 16 + i;                  // n within tile
    wt[(size_t)(nb * 64 + n) * K_DIM + kb * 64 + k] = tile[k][n];
  }
}

// ---------- per-column bias, interleaved layout: col j = 3d+k ----------
__global__ void k_biascol(const float* __restrict__ bias, float* __restrict__ bc) {
  int j = blockIdx.x * blockDim.x + threadIdx.x;
  if (j >= N_DIM) return;
  int d = j / 3;
  int k = j - 3 * d;
  float v = 0.f;
  if (k == 1) v = bias[d];
  else if (k == 2) v = bias[D_DIM + d];
  bc[j] = v;
}

// ---------- 256x256 8-phase bf16 MFMA GEMM (T1+T2+T3+T4+T5), bn-fast ----------
__global__ __launch_bounds__(512, 2) void k_gemm(
    const unsigned short* __restrict__ A,
    const unsigned short* __restrict__ BT,
    const float* __restrict__ bc,
    unsigned short* __restrict__ C,
    int Mtiles)
{
  __shared__ unsigned short smem[65536];

  // --- block swizzle (bijective, 8 XCDs); bn fast so same-XCD neighbors share A panel
  const int nwg = gridDim.x;
  const int q8 = nwg >> 3, r8 = nwg & 7;
  const int xcd = blockIdx.x & 7, li = blockIdx.x >> 3;
  const int wg = (xcd < r8 ? xcd * (q8 + 1) : r8 * (q8 + 1) + (xcd - r8) * q8) + li;
  const int NT = N_DIM / 256;   // 12
  const int bn = wg % NT;
  const int bm = wg / NT;

  const int t  = threadIdx.x;
  const int w  = t >> 6;
  const int l  = t & 63;
  const int wr = w >> 2, wc = w & 3;
  const int wrb = wr * 128, wcb = wc * 64;
  const int l15 = l & 15, lg = l >> 4, lx = l & 7;
  const int kgp0 = (lg ^ lx) * 8;          // elem offset of ksub=0 octet
  const int kgp1 = ((4 + lg) ^ lx) * 8;    // ksub=1
  const int sr0 = w * 8 + (l >> 3);        // staging row within half
  const int kgs = (lx ^ (l >> 3)) * 8;     // swizzled source k-octet

  const unsigned short* Abase = A  + (size_t)(bm * 256) * K_DIM;
  const unsigned short* Bbase = BT + (size_t)(bn * 256) * K_DIM;

  f32x4 acc[8][4];
#pragma unroll
  for (int i = 0; i < 8; ++i)
#pragma unroll
    for (int j = 0; j < 4; ++j) acc[i][j] = f32x4{0.f, 0.f, 0.f, 0.f};

#define STAGE(G, growbase, T, ldsBase)                                                  \
  { const unsigned short* s0_ = (G) + (((size_t)((growbase) + sr0)) << 10) + (T) * 64 + kgs; \
    __builtin_amdgcn_global_load_lds((gq_t)s0_, (lq_t)&smem[(ldsBase) + w * 512], 16, 0, 0); \
    const unsigned short* s1_ = s0_ + (64 << 10);                                       \
    __builtin_amdgcn_global_load_lds((gq_t)s1_, (lq_t)&smem[(ldsBase) + 4096 + w * 512], 16, 0, 0); }

#define SB0(T, b) STAGE(Bbase, 0,   (T), (b) * 32768 + 16384)
#define SB1(T, b) STAGE(Bbase, 128, (T), (b) * 32768 + 16384 + 8192)
#define SA0(T, b) STAGE(Abase, 0,   (T), (b) * 32768)
#define SA1(T, b) STAGE(Abase, 128, (T), (b) * 32768 + 8192)

#define LDF(idx) __builtin_bit_cast(bf16x8, *reinterpret_cast<const ushort8*>(&smem[(idx)]))

  // ---- prologue: tile0 fully + SB0(1); wait tile0, SB0(1) stays in flight
  SB0(0, 0); SB1(0, 0); SA0(0, 0); SA1(0, 0); SB0(1, 1);
  asm volatile("s_waitcnt vmcnt(2)" ::: "memory");
  __builtin_amdgcn_s_barrier();

#pragma unroll 2
  for (int t0 = 0; t0 < 16; ++t0) {
    const int cur = t0 & 1, nxt = cur ^ 1;
    const int cA = cur * 32768, cB = cA + 16384;
    bf16x8 bfr[4][2];
#pragma unroll
    for (int q = 0; q < 4; ++q) {
      bf16x8 af[2][2];
      if (q == 0) {
#pragma unroll
        for (int nf = 0; nf < 4; ++nf) {
          const int nr = (wcb + nf * 16 + l15) * 64;
          bfr[nf][0] = LDF(cB + nr + kgp0);
          bfr[nf][1] = LDF(cB + nr + kgp1);
        }
      }
#pragma unroll
      for (int mf = 0; mf < 2; ++mf) {
        const int ar = (wrb + (q * 2 + mf) * 16 + l15) * 64;
        af[mf][0] = LDF(cA + ar + kgp0);
        af[mf][1] = LDF(cA + ar + kgp1);
      }
      if (q == 0 && t0 < 15) SB1(t0 + 1, nxt);
      if (q == 1 && t0 < 15) SA0(t0 + 1, nxt);
      if (q == 2 && t0 < 15) SA1(t0 + 1, nxt);
      if (q == 3 && t0 < 14) SB0(t0 + 2, cur);

      __builtin_amdgcn_s_barrier();
      __builtin_amdgcn_s_setprio(1);
#pragma unroll
      for (int mf = 0; mf < 2; ++mf)
#pragma unroll
        for (int nf = 0; nf < 4; ++nf) {
          acc[q * 2 + mf][nf] = __builtin_amdgcn_mfma_f32_16x16x32_bf16(af[mf][0], bfr[nf][0], acc[q * 2 + mf][nf], 0, 0, 0);
          acc[q * 2 + mf][nf] = __builtin_amdgcn_mfma_f32_16x16x32_bf16(af[mf][1], bfr[nf][1], acc[q * 2 + mf][nf], 0, 0, 0);
        }
      __builtin_amdgcn_s_setprio(0);
      if (q == 3) {
        if (t0 < 14)       asm volatile("s_waitcnt vmcnt(2)" ::: "memory");
        else if (t0 == 14) asm volatile("s_waitcnt vmcnt(0)" ::: "memory");
      }
      __builtin_amdgcn_s_barrier();
      __builtin_amdgcn_sched_barrier(0);
    }
  }

  // ---- epilogue: bias add, f32->bf16, store
  const int r4 = lg * 4;
  float badd[4];
#pragma unroll
  for (int nf = 0; nf < 4; ++nf) badd[nf] = bc[bn * 256 + wcb + nf * 16 + l15];
#pragma unroll
  for (int fm = 0; fm < 8; ++fm) {
    const int row = bm * 256 + wrb + fm * 16 + r4;
#pragma unroll
    for (int nf = 0; nf < 4; ++nf) {
      const int col = bn * 256 + wcb + nf * 16 + l15;
      unsigned short* out = C + (size_t)row * N_DIM + col;
#pragma unroll
      for (int i = 0; i < 4; ++i)
        out[(size_t)i * N_DIM] = f2bf(acc[fm][nf][i] + badd[nf]);
    }
  }
#undef STAGE
#undef SB0
#undef SB1
#undef SA0
#undef SA1
#undef LDF
}

// ---------- SRU recurrence: block-phased LDS-ring async scan ----------
// 1 wave/block, 128 chains/block (2/thread). Ring: 32 slots x 1KB LDS.
// 16-step blocks: issue 16 stages -> compute 16 steps from LDS (no waits,
// h kept in regs) -> 16 coalesced stores -> ONE vmcnt(16) (leaves this
// block's 16 stores outstanding; forces next block's stages complete).
// Store-aware: stores count toward vmcnt, accounting is uniform per block.
__global__ __launch_bounds__(64) void k_rec(
    const unsigned short* __restrict__ xb,  // chunk (Lc, BD) bf16
    const unsigned short* __restrict__ u3,  // chunk (Lc*32, 3072) bf16, j=3d+k
    const float* __restrict__ wcv,
    const float* __restrict__ sxp,
    float* __restrict__ c_state,            // (BD)
    float* __restrict__ h,                  // chunk base (Lc, BD) f32
    int Lc)
{
  __shared__ unsigned int lds_u32[32 * 256];   // 32 slots x 1024 B

  const int ln = threadIdx.x;                  // lane 0..63
  const int bi = blockIdx.x;                   // 0..255
  const int b  = bi >> 3;                      // batch 0..31
  const int d0 = (bi & 7) * 128;               // chain base within batch
  const int d  = d0 + 2 * ln;
  const int ci = b * D_DIM + d;

  const float fw0 = wcv[d],         fw1 = wcv[d + 1];
  const float rw0 = wcv[D_DIM + d], rw1 = wcv[D_DIM + d + 1];
  const float sx = sxp[0];
  float c0 = c_state[ci], c1 = c_state[ci + 1];

  const int ub_off = b * N_DIM + 3 * d0;       // ushort offset of block's u3 slice in a step row
  const int xw_off = b * D_DIM + d0;           // ushort offset of block's x slice

#define RSTAGE(ls)                                                                       \
  { const int slot_ = (ls) & 31;                                                         \
    const unsigned short* us_ = u3 + (size_t)(ls) * S3 + ub_off + ln * 8;                \
    const unsigned short* xs_ = xb + (size_t)(ls) * BD + xw_off + (ln - 48) * 8;         \
    const unsigned short* src_ = (ln < 48) ? us_ : xs_;                                  \
    __builtin_amdgcn_global_load_lds((gq_t)src_, (lq_t)(lds_u32 + slot_ * 256), 16, 0, 0); }

  // prologue: stage steps 0..15, drain once
#pragma unroll
  for (int i = 0; i < 16; ++i) RSTAGE(i)
  asm volatile("s_waitcnt vmcnt(0)" ::: "memory");

  float* hp = h + ci;
  for (int B = 0; B < Lc; B += 16) {
    // issue next block's 16 stages (wrap past Lc: L2-hot re-stage, opposite ring half)
#pragma unroll
    for (int i = 0; i < 16; ++i) {
      int ls = B + 16 + i;
      if (ls >= Lc) ls -= Lc;
      RSTAGE(ls)
    }

    float2 hv[16];
#pragma unroll
    for (int i = 0; i < 16; ++i) {
      const int sb = ((B + i) & 31) * 256;
      const unsigned w0 = lds_u32[sb + ln * 3 + 0];   // u0(d), u1(d)
      const unsigned w1 = lds_u32[sb + ln * 3 + 1];   // u2(d), u0(d+1)
      const unsigned w2 = lds_u32[sb + ln * 3 + 2];   // u1(d+1), u2(d+1)
      const unsigned xw = lds_u32[sb + 192 + ln];     // x(d), x(d+1)

      float u0a = bf2f((unsigned short)w0);
      float u1a = bf2f((unsigned short)(w0 >> 16));
      float u2a = bf2f((unsigned short)w1);
      float u0b = bf2f((unsigned short)(w1 >> 16));
      float u1b = bf2f((unsigned short)w2);
      float u2b = bf2f((unsigned short)(w2 >> 16));
      float xa = bf2f((unsigned short)xw) * sx;
      float xv = bf2f((unsigned short)(xw >> 16)) * sx;

      float f0 = 1.f / (1.f + __expf(-(u1a + c0 * fw0)));
      float r0 = 1.f / (1.f + __expf(-(u2a + c0 * rw0)));
      c0 = u0a + (c0 - u0a) * f0;
      hv[i].x = xa + (c0 - xa) * r0;

      float f1 = 1.f / (1.f + __expf(-(u1b + c1 * fw1)));
      float r1 = 1.f / (1.f + __expf(-(u2b + c1 * rw1)));
      c1 = u0b + (c1 - u0b) * f1;
      hv[i].y = xv + (c1 - xv) * r1;
    }

    // coalesced stores of this block's h
#pragma unroll
    for (int i = 0; i < 16; ++i)
      *reinterpret_cast<float2*>(hp + (size_t)(B + i) * BD) = hv[i];

    // uniform end-of-block wait: newest 16 ops (this block's stores) may linger;
    // next block's stages and all older stores are forced complete.
    asm volatile("s_waitcnt vmcnt(16)" ::: "memory");
  }
  c_state[ci] = c0;
  c_state[ci + 1] = c1;
#undef RSTAGE
}

__global__ void k_copyc(const float* __restrict__ c_state, float* __restrict__ out) {
  int i = blockIdx.x * blockDim.x + threadIdx.x;
  if (i < BD) out[i] = c_state[i];
}

extern "C" void kernel_launch(void* const* d_in, const int* in_sizes, int n_in,
                              void* d_out, int out_size, void* d_ws, size_t ws_size,
                              hipStream_t stream) {
  const float* x    = (const float*)d_in[0];
  const float* w    = (const float*)d_in[1];
  const float* wcv  = (const float*)d_in[2];
  const float* bias = (const float*)d_in[3];
  const float* sx   = (const float*)d_in[4];
  float* hout = (float*)d_out;
  float* cout = hout + (size_t)L_DIM * BD;

  const size_t wt_bytes  = (size_t)N_DIM * K_DIM * 2;
  const size_t bc_off    = wt_bytes;
  const size_t c_off     = bc_off + (size_t)N_DIM * 4;
  const size_t xbf_off   = c_off + (size_t)BD * 4;
  const size_t xbf_bytes = (size_t)L_DIM * BD * 2;   // full-x bf16: 134 MB
  const size_t u3_off    = xbf_off + xbf_bytes;
  int Lc = 8;
  for (int cand : {512, 256, 128, 64, 32, 16, 8}) {
    size_t need = u3_off + (size_t)cand * 196608 + 1024;   // u3 chunk bf16
    if (need <= ws_size) { Lc = cand; break; }
  }
  char* wsb = (char*)d_ws;
  unsigned short* wt_p  = (unsigned short*)wsb;
  float*          bc_p  = (float*)(wsb + bc_off);
  float*          c_p   = (float*)(wsb + c_off);
  unsigned short* xbf_p = (unsigned short*)(wsb + xbf_off);
  unsigned short* u3_p  = (unsigned short*)(wsb + u3_off);

  hipMemsetAsync(c_p, 0, (size_t)BD * 4, stream);
  k_wt<<<16 * 48, 256, 0, stream>>>(w, wt_p);
  k_biascol<<<(N_DIM + 255) / 256, 256, 0, stream>>>(bias, bc_p);
  k_convx<<<(L_DIM * BD / 8) / 256, 256, 0, stream>>>(x, xbf_p, L_DIM * BD / 8);

  const int nchunks = L_DIM / Lc;
  const int Mtiles  = (Lc * B_DIM) / 256;
  for (int ci = 0; ci < nchunks; ++ci) {
    const size_t base = (size_t)ci * Lc * BD;
    k_gemm<<<Mtiles * (N_DIM / 256), 512, 0, stream>>>(xbf_p + base, wt_p, bc_p, u3_p, Mtiles);
    k_rec<<<BD / 128, 64, 0, stream>>>(xbf_p + base, u3_p, wcv, sx, c_p, hout + base, Lc);
  }
  k_copyc<<<BD / 256, 256, 0, stream>>>(c_p, cout);
}

// Round 14
// 773.397 us; speedup vs baseline: 2.6161x; 1.1721x over previous
//
#include <hip/hip_runtime.h>
#include <stdint.h>

#define L_DIM 2048
#define B_DIM 32
#define D_DIM 1024
#define N_DIM 3072   // 3*D
#define K_DIM 1024
#define BD    32768  // B*D
#define S3    (32 * N_DIM)   // u3 step stride (ushorts)

typedef __bf16 bf16x8 __attribute__((ext_vector_type(8)));
typedef unsigned short ushort8 __attribute__((ext_vector_type(8)));
typedef float f32x4 __attribute__((ext_vector_type(4)));

typedef const __attribute__((address_space(1))) unsigned int* gq_t;
typedef __attribute__((address_space(3))) unsigned int* lq_t;

static __device__ __forceinline__ unsigned short f2bf(float f) {
  unsigned u = __float_as_uint(f);
  u += 0x7FFFu + ((u >> 16) & 1u);   // RNE
  return (unsigned short)(u >> 16);
}

static __device__ __forceinline__ float bf2f(unsigned short s) {
  return __uint_as_float(((unsigned)s) << 16);
}

// ---------- convert ALL of x (f32) -> bf16, 8 elems/thread, one pass ----------
__global__ void k_convx(const float* __restrict__ x, unsigned short* __restrict__ xb, int n8) {
  int i = blockIdx.x * blockDim.x + threadIdx.x;
  if (i >= n8) return;
  const float4* p = reinterpret_cast<const float4*>(x) + (size_t)i * 2;
  float4 a = p[0], b = p[1];
  ushort8 o;
  o[0] = f2bf(a.x); o[1] = f2bf(a.y); o[2] = f2bf(a.z); o[3] = f2bf(a.w);
  o[4] = f2bf(b.x); o[5] = f2bf(b.y); o[6] = f2bf(b.z); o[7] = f2bf(b.w);
  reinterpret_cast<ushort8*>(xb)[i] = o;
}

// ---------- W (K,N=3072 interleaved 3d+k) f32 -> WT (N'=k*D+d, K) bf16 ----------
__global__ __launch_bounds__(256) void k_wt(const float* __restrict__ w, unsigned short* __restrict__ wt) {
  __shared__ unsigned short tile[64][65];
  const int bid = blockIdx.x;
  const int kb = bid & 15;          // K/64 tile
  const int db = (bid >> 4) & 15;   // D/64 tile
  const int kp = bid >> 8;          // plane 0..2
  const int t = threadIdx.x;
  const int c = t & 63;
  const int q = t >> 6;             // 0..3
#pragma unroll
  for (int i = 0; i < 16; ++i) {
    int r = q * 16 + i;             // k within tile
    float v = w[(size_t)(kb * 64 + r) * N_DIM + 3 * (db * 64 + c) + kp];
    tile[r][c] = f2bf(v);
  }
  __syncthreads();
  const int k = t & 63;
#pragma unroll
  for (int i = 0; i < 16; ++i) {
    int n = q * 16 + i;             // d within tile
    wt[(size_t)(kp * D_DIM + db * 64 + n) * K_DIM + kb * 64 + k] = tile[k][n];
  }
}

// ---------- per-column bias, plane layout: col j = k*D+d ----------
__global__ void k_biascol(const float* __restrict__ bias, float* __restrict__ bc) {
  int j = blockIdx.x * blockDim.x + threadIdx.x;
  if (j >= N_DIM) return;
  int k = j >> 10;
  int d = j & 1023;
  float v = 0.f;
  if (k == 1) v = bias[d];
  else if (k == 2) v = bias[D_DIM + d];
  bc[j] = v;
}

// ---------- 256x256 8-phase bf16 MFMA GEMM (T1+T2+T3+T4+T5), bn-fast ----------
__global__ __launch_bounds__(512, 2) void k_gemm(
    const unsigned short* __restrict__ A,
    const unsigned short* __restrict__ BT,
    const float* __restrict__ bc,
    unsigned short* __restrict__ C,
    int Mtiles)
{
  __shared__ unsigned short smem[65536];

  // --- block swizzle (bijective, 8 XCDs); bn fast so same-XCD neighbors share A panel
  const int nwg = gridDim.x;
  const int q8 = nwg >> 3, r8 = nwg & 7;
  const int xcd = blockIdx.x & 7, li = blockIdx.x >> 3;
  const int wg = (xcd < r8 ? xcd * (q8 + 1) : r8 * (q8 + 1) + (xcd - r8) * q8) + li;
  const int NT = N_DIM / 256;   // 12
  const int bn = wg % NT;
  const int bm = wg / NT;

  const int t  = threadIdx.x;
  const int w  = t >> 6;
  const int l  = t & 63;
  const int wr = w >> 2, wc = w & 3;
  const int wrb = wr * 128, wcb = wc * 64;
  const int l15 = l & 15, lg = l >> 4, lx = l & 7;
  const int kgp0 = (lg ^ lx) * 8;          // elem offset of ksub=0 octet
  const int kgp1 = ((4 + lg) ^ lx) * 8;    // ksub=1
  const int sr0 = w * 8 + (l >> 3);        // staging row within half
  const int kgs = (lx ^ (l >> 3)) * 8;     // swizzled source k-octet

  const unsigned short* Abase = A  + (size_t)(bm * 256) * K_DIM;
  const unsigned short* Bbase = BT + (size_t)(bn * 256) * K_DIM;

  f32x4 acc[8][4];
#pragma unroll
  for (int i = 0; i < 8; ++i)
#pragma unroll
    for (int j = 0; j < 4; ++j) acc[i][j] = f32x4{0.f, 0.f, 0.f, 0.f};

#define STAGE(G, growbase, T, ldsBase)                                                  \
  { const unsigned short* s0_ = (G) + (((size_t)((growbase) + sr0)) << 10) + (T) * 64 + kgs; \
    __builtin_amdgcn_global_load_lds((gq_t)s0_, (lq_t)&smem[(ldsBase) + w * 512], 16, 0, 0); \
    const unsigned short* s1_ = s0_ + (64 << 10);                                       \
    __builtin_amdgcn_global_load_lds((gq_t)s1_, (lq_t)&smem[(ldsBase) + 4096 + w * 512], 16, 0, 0); }

#define SB0(T, b) STAGE(Bbase, 0,   (T), (b) * 32768 + 16384)
#define SB1(T, b) STAGE(Bbase, 128, (T), (b) * 32768 + 16384 + 8192)
#define SA0(T, b) STAGE(Abase, 0,   (T), (b) * 32768)
#define SA1(T, b) STAGE(Abase, 128, (T), (b) * 32768 + 8192)

#define LDF(idx) __builtin_bit_cast(bf16x8, *reinterpret_cast<const ushort8*>(&smem[(idx)]))

  // ---- prologue: tile0 fully + SB0(1); wait tile0, SB0(1) stays in flight
  SB0(0, 0); SB1(0, 0); SA0(0, 0); SA1(0, 0); SB0(1, 1);
  asm volatile("s_waitcnt vmcnt(2)" ::: "memory");
  __builtin_amdgcn_s_barrier();

#pragma unroll 2
  for (int t0 = 0; t0 < 16; ++t0) {
    const int cur = t0 & 1, nxt = cur ^ 1;
    const int cA = cur * 32768, cB = cA + 16384;
    bf16x8 bfr[4][2];
#pragma unroll
    for (int q = 0; q < 4; ++q) {
      bf16x8 af[2][2];
      if (q == 0) {
#pragma unroll
        for (int nf = 0; nf < 4; ++nf) {
          const int nr = (wcb + nf * 16 + l15) * 64;
          bfr[nf][0] = LDF(cB + nr + kgp0);
          bfr[nf][1] = LDF(cB + nr + kgp1);
        }
      }
#pragma unroll
      for (int mf = 0; mf < 2; ++mf) {
        const int ar = (wrb + (q * 2 + mf) * 16 + l15) * 64;
        af[mf][0] = LDF(cA + ar + kgp0);
        af[mf][1] = LDF(cA + ar + kgp1);
      }
      if (q == 0 && t0 < 15) SB1(t0 + 1, nxt);
      if (q == 1 && t0 < 15) SA0(t0 + 1, nxt);
      if (q == 2 && t0 < 15) SA1(t0 + 1, nxt);
      if (q == 3 && t0 < 14) SB0(t0 + 2, cur);

      __builtin_amdgcn_s_barrier();
      __builtin_amdgcn_s_setprio(1);
#pragma unroll
      for (int mf = 0; mf < 2; ++mf)
#pragma unroll
        for (int nf = 0; nf < 4; ++nf) {
          acc[q * 2 + mf][nf] = __builtin_amdgcn_mfma_f32_16x16x32_bf16(af[mf][0], bfr[nf][0], acc[q * 2 + mf][nf], 0, 0, 0);
          acc[q * 2 + mf][nf] = __builtin_amdgcn_mfma_f32_16x16x32_bf16(af[mf][1], bfr[nf][1], acc[q * 2 + mf][nf], 0, 0, 0);
        }
      __builtin_amdgcn_s_setprio(0);
      if (q == 3) {
        if (t0 < 14)       asm volatile("s_waitcnt vmcnt(2)" ::: "memory");
        else if (t0 == 14) asm volatile("s_waitcnt vmcnt(0)" ::: "memory");
      }
      __builtin_amdgcn_s_barrier();
      __builtin_amdgcn_sched_barrier(0);
    }
  }

  // ---- epilogue: bias add, f32->bf16, store
  const int r4 = lg * 4;
  float badd[4];
#pragma unroll
  for (int nf = 0; nf < 4; ++nf) badd[nf] = bc[bn * 256 + wcb + nf * 16 + l15];
#pragma unroll
  for (int fm = 0; fm < 8; ++fm) {
    const int row = bm * 256 + wrb + fm * 16 + r4;
#pragma unroll
    for (int nf = 0; nf < 4; ++nf) {
      const int col = bn * 256 + wcb + nf * 16 + l15;
      unsigned short* out = C + (size_t)row * N_DIM + col;
#pragma unroll
      for (int i = 0; i < 4; ++i)
        out[(size_t)i * N_DIM] = f2bf(acc[fm][nf][i] + badd[nf]);
    }
  }
#undef STAGE
#undef SB0
#undef SB1
#undef SA0
#undef SA1
#undef LDF
}

// ---------- SRU recurrence: block-phased LDS-ring scan, 512 single-wave blocks ----------
// 1 chain/thread, 64 chains/block -> 512 waves = 2 SIMDs/CU busy (max for this op).
// Plane u3 layout (col j = k*D+d): per step a block needs u0|u1|u2|x slices of
// 128B each = 512B. ONE width-16 global_load_lds stages TWO steps (lanes 0-31 ->
// step l, lanes 32-63 -> step l+1). Ring 32 slots x 512B = 16KB LDS.
// 16-step blocks: 8 stages -> compute 16 steps from LDS -> 16 stores -> vmcnt(16).
__global__ __launch_bounds__(64) void k_rec(
    const unsigned short* __restrict__ xb,  // chunk (Lc, BD) bf16
    const unsigned short* __restrict__ u3,  // chunk (Lc*32, 3072) bf16 planes
    const float* __restrict__ wcv,
    const float* __restrict__ sxp,
    float* __restrict__ c_state,            // (BD)
    float* __restrict__ h,                  // chunk base (Lc, BD) f32
    int Lc)
{
  __shared__ unsigned short lds16[32 * 256];   // 32 slots x 512 B

  const int t  = threadIdx.x;                  // lane 0..63 = chain within block
  const int bi = blockIdx.x;                   // 0..511
  const int b  = bi >> 4;                      // batch 0..31
  const int d0 = (bi & 15) * 64;               // chain base within batch
  const int ci = b * D_DIM + d0 + t;
  const int d  = d0 + t;

  const float fw = wcv[d];
  const float rw = wcv[D_DIM + d];
  const float sx = sxp[0];
  float c = c_state[ci];

  // staging lane decomposition: sub = lane>>5 (step l2+sub), li = lane&31,
  // plane p = li>>3 (0..2 = u planes, 3 = x), off8 = li&7 (16B chunk within 128B slice)
  const int sub  = t >> 5;
  const int li   = t & 31;
  const int pp   = li >> 3;
  const int off8 = (li & 7) * 8;               // ushort offset within slice

#define RSTAGE(l2)                                                                        \
  { const int st_ = (l2) + sub;                                                           \
    const unsigned short* src_ = (pp < 3)                                                 \
      ? u3 + (size_t)st_ * S3 + b * N_DIM + pp * D_DIM + d0 + off8                        \
      : xb + (size_t)st_ * BD + b * D_DIM + d0 + off8;                                    \
    __builtin_amdgcn_global_load_lds((gq_t)src_, (lq_t)(lds16 + ((l2) & 31) * 256), 16, 0, 0); }

  // prologue: stage steps 0..15 (8 instrs), drain once
#pragma unroll
  for (int i = 0; i < 8; ++i) RSTAGE(2 * i)
  asm volatile("s_waitcnt vmcnt(0)" ::: "memory");

  float* hp = h + ci;
  for (int B = 0; B < Lc; B += 16) {
    // issue next block's 8 stages (wrap past Lc: L2-hot re-stage, opposite ring half)
#pragma unroll
    for (int i = 0; i < 8; ++i) {
      int ls = B + 16 + 2 * i;
      if (ls >= Lc) ls -= Lc;
      RSTAGE(ls)
    }

    float hv[16];
#pragma unroll
    for (int i = 0; i < 16; ++i) {
      const int sb = ((B + i) & 31) * 256;
      float u0 = bf2f(lds16[sb + t]);
      float u1 = bf2f(lds16[sb + 64 + t]);
      float u2 = bf2f(lds16[sb + 128 + t]);
      float xv = bf2f(lds16[sb + 192 + t]) * sx;

      float f = 1.f / (1.f + __expf(-(u1 + c * fw)));
      float r = 1.f / (1.f + __expf(-(u2 + c * rw)));
      c = u0 + (c - u0) * f;
      hv[i] = xv + (c - xv) * r;
    }

    // coalesced stores of this block's h
#pragma unroll
    for (int i = 0; i < 16; ++i)
      hp[(size_t)(B + i) * BD] = hv[i];

    // uniform end-of-block wait: newest 16 ops (stores) may linger;
    // next block's 8 stages and all older stores are forced complete.
    asm volatile("s_waitcnt vmcnt(16)" ::: "memory");
  }
  c_state[ci] = c;
#undef RSTAGE
}

__global__ void k_copyc(const float* __restrict__ c_state, float* __restrict__ out) {
  int i = blockIdx.x * blockDim.x + threadIdx.x;
  if (i < BD) out[i] = c_state[i];
}

extern "C" void kernel_launch(void* const* d_in, const int* in_sizes, int n_in,
                              void* d_out, int out_size, void* d_ws, size_t ws_size,
                              hipStream_t stream) {
  const float* x    = (const float*)d_in[0];
  const float* w    = (const float*)d_in[1];
  const float* wcv  = (const float*)d_in[2];
  const float* bias = (const float*)d_in[3];
  const float* sx   = (const float*)d_in[4];
  float* hout = (float*)d_out;
  float* cout = hout + (size_t)L_DIM * BD;

  const size_t wt_bytes  = (size_t)N_DIM * K_DIM * 2;
  const size_t bc_off    = wt_bytes;
  const size_t c_off     = bc_off + (size_t)N_DIM * 4;
  const size_t xbf_off   = c_off + (size_t)BD * 4;
  const size_t xbf_bytes = (size_t)L_DIM * BD * 2;   // full-x bf16: 134 MB
  const size_t u3_off    = xbf_off + xbf_bytes;
  int Lc = 8;
  for (int cand : {512, 256, 128, 64, 32, 16, 8}) {
    size_t need = u3_off + (size_t)cand * 196608 + 1024;   // u3 chunk bf16
    if (need <= ws_size) { Lc = cand; break; }
  }
  char* wsb = (char*)d_ws;
  unsigned short* wt_p  = (unsigned short*)wsb;
  float*          bc_p  = (float*)(wsb + bc_off);
  float*          c_p   = (float*)(wsb + c_off);
  unsigned short* xbf_p = (unsigned short*)(wsb + xbf_off);
  unsigned short* u3_p  = (unsigned short*)(wsb + u3_off);

  hipMemsetAsync(c_p, 0, (size_t)BD * 4, stream);
  k_wt<<<(K_DIM / 64) * (D_DIM / 64) * 3, 256, 0, stream>>>(w, wt_p);
  k_biascol<<<(N_DIM + 255) / 256, 256, 0, stream>>>(bias, bc_p);
  k_convx<<<(L_DIM * BD / 8) / 256, 256, 0, stream>>>(x, xbf_p, L_DIM * BD / 8);

  const int nchunks = L_DIM / Lc;
  const int Mtiles  = (Lc * B_DIM) / 256;
  for (int ci = 0; ci < nchunks; ++ci) {
    const size_t base = (size_t)ci * Lc * BD;
    k_gemm<<<Mtiles * (N_DIM / 256), 512, 0, stream>>>(xbf_p + base, wt_p, bc_p, u3_p, Mtiles);
    k_rec<<<512, 64, 0, stream>>>(xbf_p + base, u3_p, wcv, sx, c_p, hout + base, Lc);
  }
  k_copyc<<<BD / 256, 256, 0, stream>>>(c_p, cout);
}